// Round 17
// baseline (572.987 us; speedup 1.0000x reference)
//
#include <hip/hip_runtime.h>

#define L  2048
#define D  64
#define NH 16
#define NB 2
#define KT 64
#define NT 32
#define LOG2E 1.44269504088896f

using half8   = _Float16 __attribute__((ext_vector_type(8)));
using half4v  = _Float16 __attribute__((ext_vector_type(4)));
using float4v = float    __attribute__((ext_vector_type(4)));
using int4v   = int      __attribute__((ext_vector_type(4)));

#define BAR()    asm volatile("s_barrier" ::: "memory")
#define WAITV(n) asm volatile("s_waitcnt vmcnt(" #n ")" ::: "memory")
#define WAITL()  asm volatile("s_waitcnt lgkmcnt(0)" ::: "memory")

__device__ __forceinline__ void gload16(const void* g, void* l) {
    __builtin_amdgcn_global_load_lds((const __attribute__((address_space(1))) void*)g,
                                     (__attribute__((address_space(3))) void*)l, 16, 0, 0);
}

// ---------------- precompute: qh = fp16(q * log2e/8), kh = fp16(k) ----------------
__global__ __launch_bounds__(256) void prep_qk(const float* __restrict__ q,
                                               const float* __restrict__ k,
                                               _Float16* __restrict__ qh,
                                               _Float16* __restrict__ kh) {
    int i = (blockIdx.x * 256 + threadIdx.x) * 8;
    float4v a0 = *(const float4v*)(q + i);
    float4v a1 = *(const float4v*)(q + i + 4);
    float4v b0 = *(const float4v*)(k + i);
    float4v b1 = *(const float4v*)(k + i + 4);
    half8 qo, ko;
    const float s = 0.125f * LOG2E;
#pragma unroll
    for (int j = 0; j < 4; ++j) {
        qo[j]     = (_Float16)(a0[j] * s);
        qo[4 + j] = (_Float16)(a1[j] * s);
        ko[j]     = (_Float16)b0[j];
        ko[4 + j] = (_Float16)b1[j];
    }
    *(half8*)(qh + i) = qo;
    *(half8*)(kh + i) = ko;
}

// ------- precompute: vt2[bh][kb(128)][d(64)][kl(16)] = fp16(v[b,h,kb*16+kl,d]) -------
__global__ __launch_bounds__(256) void prep_vt(const float* __restrict__ v,
                                               _Float16* __restrict__ vt) {
    __shared__ float tile[64][65];
    int bh = blockIdx.x >> 5;
    int l0 = (blockIdx.x & 31) * 64;
    const float* vb = v + (size_t)bh * L * D + (size_t)l0 * D;
    int row = threadIdx.x >> 2, c0 = (threadIdx.x & 3) * 16;
#pragma unroll
    for (int j = 0; j < 16; j += 4) {
        float4v t4 = *(const float4v*)(vb + row * D + c0 + j);
        tile[row][c0 + j + 0] = t4[0];
        tile[row][c0 + j + 1] = t4[1];
        tile[row][c0 + j + 2] = t4[2];
        tile[row][c0 + j + 3] = t4[3];
    }
    __syncthreads();
    int d = threadIdx.x >> 2, kbl = threadIdx.x & 3;
    int lq = kbl * 16;
    _Float16* ob = vt + (((size_t)bh * 128 + (l0 >> 4) + kbl) * 64 + d) * 16;
    half8 o0, o1;
#pragma unroll
    for (int j = 0; j < 8; ++j) {
        o0[j] = (_Float16)tile[lq + j][d];
        o1[j] = (_Float16)tile[lq + 8 + j][d];
    }
    *(half8*)(ob)     = o0;
    *(half8*)(ob + 8) = o1;
}

// ------- precompute: mbh2[b][qt(128)][t(32)][w(4)][row(16)][kl(16)] -------
__global__ __launch_bounds__(256) void prep_mbh(const int* __restrict__ mask,
                                                const float* __restrict__ bias,
                                                _Float16* __restrict__ mbh) {
    int blk = blockIdx.x;
    int bq = blk >> 3, tg = blk & 7;
    int b  = bq >> 7, qt = bq & 127;
    int row = threadIdx.x >> 4;
    int c16 = threadIdx.x & 15;
    const int*   mrow = mask + ((size_t)b * L + qt * 16 + row) * L;
    const float* brow = bias + ((size_t)b * L + qt * 16 + row) * L;
    _Float16* obase = mbh + (size_t)bq * 32768 + (c16 >> 2) * 256 + row * 16 + (c16 & 3) * 4;
#pragma unroll
    for (int tt = 0; tt < 4; ++tt) {
        int t = tg * 4 + tt;
        int key = t * 64 + c16 * 4;
        int4v   m  = *(const int4v*)(mrow + key);
        float4v bb = *(const float4v*)(brow + key);
        half4v o;
        o[0] = m[0] ? (_Float16)(bb[0] * LOG2E) : (_Float16)(-1500.0f);
        o[1] = m[1] ? (_Float16)(bb[1] * LOG2E) : (_Float16)(-1500.0f);
        o[2] = m[2] ? (_Float16)(bb[2] * LOG2E) : (_Float16)(-1500.0f);
        o[3] = m[3] ? (_Float16)(bb[3] * LOG2E) : (_Float16)(-1500.0f);
        *(half4v*)(obase + t * 1024) = o;
    }
}

// BODY: one loop1 iteration for tile T (T must be a LITERAL so puh[T] stays
// in registers).
#define BODY(T, MV)                                                           \
    {                                                                         \
        const _Float16* kb_ = kbw + ((T) & 1) * 1024;                         \
        const _Float16* vb_ = vbw + ((T) & 1) * 1024;                         \
        half8 bk0_ = *(const half8*)(kb_ + kro + ks0);                        \
        half8 bk1_ = *(const half8*)(kb_ + kro + ks1);                        \
        float4v acc_;                                                         \
        acc_[0] = (float)(MV)[0]; acc_[1] = (float)(MV)[1];                   \
        acc_[2] = (float)(MV)[2]; acc_[3] = (float)(MV)[3];                   \
        __builtin_amdgcn_s_setprio(1);                                        \
        acc_ = __builtin_amdgcn_mfma_f32_16x16x32_f16(bk0_, aq0, acc_, 0, 0, 0); \
        acc_ = __builtin_amdgcn_mfma_f32_16x16x32_f16(bk1_, aq1, acc_, 0, 0, 0); \
        __builtin_amdgcn_s_setprio(0);                                        \
        float e0_ = exp2f(acc_[0]), e1_ = exp2f(acc_[1]);                     \
        float e2_ = exp2f(acc_[2]), e3_ = exp2f(acc_[3]);                     \
        ls += (e0_ + e1_) + (e2_ + e3_);                                      \
        half4v ph_;                                                           \
        ph_[0] = (_Float16)(e0_ * 0.03125f); ph_[1] = (_Float16)(e1_ * 0.03125f); \
        ph_[2] = (_Float16)(e2_ * 0.03125f); ph_[3] = (_Float16)(e3_ * 0.03125f); \
        puh[(T)] = ph_;                                                       \
        half4v pv0_ = *(const half4v*)(vb_ + (cg +  0) * 16 + vro);           \
        half4v pv1_ = *(const half4v*)(vb_ + (cg + 16) * 16 + vro);           \
        half4v pv2_ = *(const half4v*)(vb_ + (cg + 32) * 16 + vro);           \
        half4v pv3_ = *(const half4v*)(vb_ + (cg + 48) * 16 + vro);           \
        __builtin_amdgcn_s_setprio(1);                                        \
        oa0 = __builtin_amdgcn_mfma_f32_16x16x16f16(ph_, pv0_, oa0, 0, 0, 0); \
        oa1 = __builtin_amdgcn_mfma_f32_16x16x16f16(ph_, pv1_, oa1, 0, 0, 0); \
        oa2 = __builtin_amdgcn_mfma_f32_16x16x16f16(ph_, pv2_, oa2, 0, 0, 0); \
        oa3 = __builtin_amdgcn_mfma_f32_16x16x16f16(ph_, pv3_, oa3, 0, 0, 0); \
        __builtin_amdgcn_s_setprio(0);                                        \
    }

// Phase A step (literal T): prefetch T+1, wait ledger (st(T)4 + m(T)1 drained,
// st(T+1)4 + m(T+1)1 in flight), compute T.
#define PA(T)                                                                 \
    if ((T) + 1 < NT) {                                                       \
        stage((T) + 1, ((T) & 1) ^ 1);                                        \
        mnxt = *(const half4v*)(mg0 + (size_t)((T) + 1) * 1024 + moff);       \
        WAITV(5);                                                             \
    } else { WAITV(0); }                                                      \
    BODY((T), mcur);                                                          \
    mcur = mnxt;

// Phase B: store group J (qt0 tiles 2J,2J+1) || loop1(qt1) iters 2J,2J+1.
// Ledger (incl. m-loads): before BODY(2J): Q=[st(2J)4,m(2J)1,NT2,st(2J+1)4,
// m(2J+1)1]=12, WAITV(7) drains st(2J)+m(2J). Before BODY(2J+1): WAITV(5)
// drains NT2+... leaving st(2J+2)4+m(2J+2)1.
#define PBST(J, TL)                                                           \
    {                                                                         \
        half4v p4_ = puh[2*(J)+(TL)];                                         \
        float4v pn_;                                                          \
        pn_[0] = (float)p4_[0] * rl0; pn_[1] = (float)p4_[1] * rl0;           \
        pn_[2] = (float)p4_[2] * rl0; pn_[3] = (float)p4_[3] * rl0;           \
        int g_ = (TL) * 16 + w * 4 + grp;                                     \
        *(float4v*)(t32B + cg * 128 + ((g_ ^ (cg & 7)) * 4)) = pn_;           \
    }
#define PBRD(J, K)                                                            \
    {                                                                         \
        int gr_ = ((K) * 16 + sjj) ^ (srow & 7);                              \
        float4v s_ = *(const float4v*)(t32B + srow * 128 + gr_ * 4);          \
        __builtin_nontemporal_store(s_,                                       \
            (float4v*)(arow0 + (size_t)srow * L + (J) * 128 + ((K) * 16 + sjj) * 4)); \
    }
#define PB(J)                                                                 \
    PBST(J, 0) PBST(J, 1)                                                     \
    WAITL(); BAR();                                                           \
    PBRD(J, 0) PBRD(J, 1)                                                     \
    BAR();                                                                    \
    if (2*(J) + 1 < NT) {                                                     \
        stage(2*(J) + 1, ((2*(J)) & 1) ^ 1);                                  \
        mnxt = *(const half4v*)(mg1 + (size_t)(2*(J) + 1) * 1024 + moff);     \
        WAITV(7);                                                             \
    } else { WAITV(0); }                                                      \
    BODY(2*(J), mcur);                                                        \
    mcur = mnxt;                                                              \
    if (2*(J) + 2 < NT) {                                                     \
        stage(2*(J) + 2, ((2*(J) + 1) & 1) ^ 1);                              \
        mnxt = *(const half4v*)(mg1 + (size_t)(2*(J) + 2) * 1024 + moff);     \
        WAITV(5);                                                             \
    } else { WAITV(0); }                                                      \
    BODY(2*(J) + 1, mcur);                                                    \
    mcur = mnxt;

// Phase C: R13 store loop, literal PH.
#define PCW(PH, I)                                                            \
    {                                                                         \
        half4v p4_ = puh[(PH)*4 + (I)];                                       \
        float4v pn_;                                                          \
        pn_[0] = (float)p4_[0] * rl1; pn_[1] = (float)p4_[1] * rl1;           \
        pn_[2] = (float)p4_[2] * rl1; pn_[3] = (float)p4_[3] * rl1;           \
        int g_ = ((I) * 16 + gbase) ^ (cg & 7);                               \
        *(float4v*)(tbC + cg * 256 + g_ * 4) = pn_;                           \
    }
#define PCR(PH, K)                                                            \
    {                                                                         \
        int g_ = (sjj + 16 * (K)) ^ (srow & 7);                               \
        float4v s_ = *(const float4v*)(tbC + srow * 256 + g_ * 4);            \
        __builtin_nontemporal_store(s_,                                       \
            (float4v*)(arow1 + (size_t)srow * L + (PH) * 256 + (sjj + 16 * (K)) * 4)); \
    }
#define PC(PH)                                                                \
    {                                                                         \
        float* tbC = t32C + ((PH) & 1) * 4096;                                \
        PCW(PH, 0) PCW(PH, 1) PCW(PH, 2) PCW(PH, 3)                           \
        WAITL(); BAR();                                                       \
        PCR(PH, 0) PCR(PH, 1) PCR(PH, 2) PCR(PH, 3)                           \
    }

// ---------------- fused attention: 2 q-tiles/block, phase-overlapped ----------------
__global__ __launch_bounds__(256, 4) void attn_fused(const _Float16* __restrict__ qh,
                                                     const _Float16* __restrict__ kh,
                                                     const _Float16* __restrict__ vt,
                                                     const _Float16* __restrict__ mbh,
                                                     float* __restrict__ out_ho,
                                                     float* __restrict__ out_attn) {
    __shared__ __align__(16) char arena[40960];

    int p  = blockIdx.x;                  // XCD x: 4 heads of one b
    int l  = (p & 7) * 256 + (p >> 3);
    int b  = l >> 10, h = (l >> 6) & 15, qp = l & 63;
    int bh = b * NH + h;
    int q0 = qp * 32;

    int tid = threadIdx.x, w = tid >> 6, lane = tid & 63;
    int cg = lane & 15, grp = lane >> 4;

    const _Float16* kg  = kh  + (size_t)bh * L * D;
    const _Float16* vg  = vt  + (size_t)bh * 131072;
    const _Float16* mg0 = mbh + (size_t)(b * 128 + qp * 2) * 32768;
    const _Float16* mg1 = mg0 + 32768;
    const _Float16* qg  = qh  + ((size_t)bh * L + q0) * D;

    _Float16* kbw   = (_Float16*)(arena)         + w * 2048;  // 2 bufs x 1024 halfs
    _Float16* vbw   = (_Float16*)(arena + 16384) + w * 2048;
    float*    t32B  = (float*)(arena + 32768);                // [16][128] (phase B)
    float*    lpart = (float*)(arena + 32768);                // alias, boundaries only
    float*    rls   = (float*)(arena + 33024);                // alias, boundaries only

    const int r8  = lane >> 3;
    const int kch = ((lane & 7) ^ r8) * 8;

    auto stage = [&](int t, int bs) {
        int kb = t * 4 + w;
        int k0 = kb * 16;
        _Float16* kd = kbw + bs * 1024;
        gload16(kg + (size_t)(k0 +     r8) * D + kch, kd);
        gload16(kg + (size_t)(k0 + 8 + r8) * D + kch, kd + 512);
        _Float16* vd = vbw + bs * 1024;
        const _Float16* vs = vg + (size_t)kb * 1024;
        gload16(vs + lane * 8, vd);
        gload16(vs + 512 + lane * 8, vd + 512);
    };

    const int kro  = cg * 64;
    const int ks0  = ((grp)     ^ (cg & 7)) * 8;
    const int ks1  = ((4 + grp) ^ (cg & 7)) * 8;
    const int vro  = grp * 4;
    const int moff = w * 256 + cg * 16 + grp * 4;
    const int srow = tid >> 4, sjj = tid & 15;

    half8 aq0 = *(const half8*)(qg + cg * D + grp * 8);
    half8 aq1 = *(const half8*)(qg + cg * D + 32 + grp * 8);

    half4v puh[NT];
    float ls = 0.f;
    float4v oa0 = {0,0,0,0}, oa1 = {0,0,0,0}, oa2 = {0,0,0,0}, oa3 = {0,0,0,0};

    auto ho_epilogue = [&](int row0, float* ored) {
        float* orw = ored + w * 1088;     // [4][16][68]
#pragma unroll
        for (int r = 0; r < 4; ++r) {
            orw[(grp * 4 + r) * 68 +  0 + cg] = oa0[r];
            orw[(grp * 4 + r) * 68 + 16 + cg] = oa1[r];
            orw[(grp * 4 + r) * 68 + 32 + cg] = oa2[r];
            orw[(grp * 4 + r) * 68 + 48 + cg] = oa3[r];
        }
        __syncthreads();
        int qr = tid >> 4, d4 = (tid & 15) * 4;
        float4v s0 = *(const float4v*)(ored + 0 * 1088 + qr * 68 + d4);
        float4v s1 = *(const float4v*)(ored + 1 * 1088 + qr * 68 + d4);
        float4v s2 = *(const float4v*)(ored + 2 * 1088 + qr * 68 + d4);
        float4v s3 = *(const float4v*)(ored + 3 * 1088 + qr * 68 + d4);
        float rlo = rls[qr];
        float4v oo;
        oo[0] = ((s0[0] + s1[0]) + (s2[0] + s3[0])) * rlo;
        oo[1] = ((s0[1] + s1[1]) + (s2[1] + s3[1])) * rlo;
        oo[2] = ((s0[2] + s1[2]) + (s2[2] + s3[2])) * rlo;
        oo[3] = ((s0[3] + s1[3]) + (s2[3] + s3[3])) * rlo;
        __builtin_nontemporal_store(oo, (float4v*)(out_ho + ((size_t)bh * L + row0 + qr) * D + d4));
    };

    // ================= phase A: loop1(qt0), barrier-free =================
    half4v mcur, mnxt;
    stage(0, 0);
    mcur = *(const half4v*)(mg0 + moff);
    PA(0)  PA(1)  PA(2)  PA(3)  PA(4)  PA(5)  PA(6)  PA(7)
    PA(8)  PA(9)  PA(10) PA(11) PA(12) PA(13) PA(14) PA(15)
    PA(16) PA(17) PA(18) PA(19) PA(20) PA(21) PA(22) PA(23)
    PA(24) PA(25) PA(26) PA(27) PA(28) PA(29) PA(30) PA(31)

    ls += __shfl_xor(ls, 16);
    ls += __shfl_xor(ls, 32);
    if (grp == 0) lpart[w * 16 + cg] = ls;
    __syncthreads();
    float rl0 = 32.0f / ((lpart[cg] + lpart[16 + cg]) + (lpart[32 + cg] + lpart[48 + cg]));
    if (w == 0 && grp == 0) rls[cg] = rl0;
    __syncthreads();
    ho_epilogue(q0, (float*)arena);       // ored aliases staging (dead)
    __syncthreads();                       // before qt1 staging overwrites

    // ================= phase B: stores(qt0) || loop1(qt1) =================
    aq0 = *(const half8*)(qg + (16 + cg) * D + grp * 8);
    aq1 = *(const half8*)(qg + (16 + cg) * D + 32 + grp * 8);
    oa0 = oa1 = oa2 = oa3 = float4v{0, 0, 0, 0};
    ls = 0.f;
    float* arow0 = out_attn + ((size_t)bh * L + q0) * L;

    stage(0, 0);
    mcur = *(const half4v*)(mg1 + moff);
    PB(0)  PB(1)  PB(2)  PB(3)  PB(4)  PB(5)  PB(6)  PB(7)
    PB(8)  PB(9)  PB(10) PB(11) PB(12) PB(13) PB(14) PB(15)

    ls += __shfl_xor(ls, 16);
    ls += __shfl_xor(ls, 32);
    if (grp == 0) lpart[w * 16 + cg] = ls;
    __syncthreads();
    float rl1 = 32.0f / ((lpart[cg] + lpart[16 + cg]) + (lpart[32 + cg] + lpart[48 + cg]));
    if (w == 0 && grp == 0) rls[cg] = rl1;
    __syncthreads();
    ho_epilogue(q0 + 16, (float*)arena);
    __syncthreads();                       // before t32C overwrites ored

    // ================= phase C: loop2(qt1), R13 store loop =================
    float* arow1 = out_attn + ((size_t)bh * L + q0 + 16) * L;
    float* t32C  = (float*)arena;          // dbuf [2][16][256]
    const int gbase = w * 4 + grp;
    PC(0) PC(1) PC(2) PC(3) PC(4) PC(5) PC(6) PC(7)
}

extern "C" void kernel_launch(void* const* d_in, const int* in_sizes, int n_in,
                              void* d_out, int out_size, void* d_ws, size_t ws_size,
                              hipStream_t stream) {
    const float* q    = (const float*)d_in[0];
    const float* k    = (const float*)d_in[1];
    const float* v    = (const float*)d_in[2];
    const int*   mask = (const int*)d_in[3];
    const float* bias = (const float*)d_in[4];

    float* ho   = (float*)d_out;
    float* attn = (float*)d_out + (size_t)NB * NH * L * D;

    char* ws = (char*)d_ws;
    _Float16* qh  = (_Float16*)(ws);                       //  8 MB
    _Float16* kh  = (_Float16*)(ws + ((size_t)8  << 20));  //  8 MB
    _Float16* vt  = (_Float16*)(ws + ((size_t)16 << 20));  //  8 MB (tiled)
    _Float16* mbh = (_Float16*)(ws + ((size_t)24 << 20));  // 16.8 MB (tiled)
    (void)in_sizes; (void)n_in; (void)out_size; (void)ws_size;

    prep_qk<<<2048, 256, 0, stream>>>(q, k, qh, kh);
    prep_vt<<<1024, 256, 0, stream>>>(v, vt);
    prep_mbh<<<2048, 256, 0, stream>>>(mask, bias, mbh);
    attn_fused<<<2048, 256, 0, stream>>>(qh, kh, vt, mbh, ho, attn);
}

// Round 18
// 431.372 us; speedup vs baseline: 1.3283x; 1.3283x over previous
//
#include <hip/hip_runtime.h>

#define L  2048
#define D  64
#define NH 16
#define NB 2
#define KT 64
#define NT 32
#define LOG2E 1.44269504088896f

using half8   = _Float16 __attribute__((ext_vector_type(8)));
using half4v  = _Float16 __attribute__((ext_vector_type(4)));
using float4v = float    __attribute__((ext_vector_type(4)));
using int4v   = int      __attribute__((ext_vector_type(4)));

#define BAR()    asm volatile("s_barrier" ::: "memory")
#define WAITV(n) asm volatile("s_waitcnt vmcnt(" #n ")" ::: "memory")
#define WAITL()  asm volatile("s_waitcnt lgkmcnt(0)" ::: "memory")

__device__ __forceinline__ void gload16(const void* g, void* l) {
    __builtin_amdgcn_global_load_lds((const __attribute__((address_space(1))) void*)g,
                                     (__attribute__((address_space(3))) void*)l, 16, 0, 0);
}

// ---------------- precompute: qh = fp16(q * log2e/8), kh = fp16(k) ----------------
__global__ __launch_bounds__(256) void prep_qk(const float* __restrict__ q,
                                               const float* __restrict__ k,
                                               _Float16* __restrict__ qh,
                                               _Float16* __restrict__ kh) {
    int i = (blockIdx.x * 256 + threadIdx.x) * 8;
    float4v a0 = *(const float4v*)(q + i);
    float4v a1 = *(const float4v*)(q + i + 4);
    float4v b0 = *(const float4v*)(k + i);
    float4v b1 = *(const float4v*)(k + i + 4);
    half8 qo, ko;
    const float s = 0.125f * LOG2E;
#pragma unroll
    for (int j = 0; j < 4; ++j) {
        qo[j]     = (_Float16)(a0[j] * s);
        qo[4 + j] = (_Float16)(a1[j] * s);
        ko[j]     = (_Float16)b0[j];
        ko[4 + j] = (_Float16)b1[j];
    }
    *(half8*)(qh + i) = qo;
    *(half8*)(kh + i) = ko;
}

// ------- precompute: vt2[bh][kb(128)][d(64)][kl(16)] = fp16(v[b,h,kb*16+kl,d]) -------
__global__ __launch_bounds__(256) void prep_vt(const float* __restrict__ v,
                                               _Float16* __restrict__ vt) {
    __shared__ float tile[64][65];
    int bh = blockIdx.x >> 5;
    int l0 = (blockIdx.x & 31) * 64;
    const float* vb = v + (size_t)bh * L * D + (size_t)l0 * D;
    int row = threadIdx.x >> 2, c0 = (threadIdx.x & 3) * 16;
#pragma unroll
    for (int j = 0; j < 16; j += 4) {
        float4v t4 = *(const float4v*)(vb + row * D + c0 + j);
        tile[row][c0 + j + 0] = t4[0];
        tile[row][c0 + j + 1] = t4[1];
        tile[row][c0 + j + 2] = t4[2];
        tile[row][c0 + j + 3] = t4[3];
    }
    __syncthreads();
    int d = threadIdx.x >> 2, kbl = threadIdx.x & 3;
    int lq = kbl * 16;
    _Float16* ob = vt + (((size_t)bh * 128 + (l0 >> 4) + kbl) * 64 + d) * 16;
    half8 o0, o1;
#pragma unroll
    for (int j = 0; j < 8; ++j) {
        o0[j] = (_Float16)tile[lq + j][d];
        o1[j] = (_Float16)tile[lq + 8 + j][d];
    }
    *(half8*)(ob)     = o0;
    *(half8*)(ob + 8) = o1;
}

// ------- precompute: mbh2[b][qt(128)][t(32)][w(4)][row(16)][kl(16)] -------
__global__ __launch_bounds__(256) void prep_mbh(const int* __restrict__ mask,
                                                const float* __restrict__ bias,
                                                _Float16* __restrict__ mbh) {
    int blk = blockIdx.x;
    int bq = blk >> 3, tg = blk & 7;
    int b  = bq >> 7, qt = bq & 127;
    int row = threadIdx.x >> 4;
    int c16 = threadIdx.x & 15;
    const int*   mrow = mask + ((size_t)b * L + qt * 16 + row) * L;
    const float* brow = bias + ((size_t)b * L + qt * 16 + row) * L;
    _Float16* obase = mbh + (size_t)bq * 32768 + (c16 >> 2) * 256 + row * 16 + (c16 & 3) * 4;
#pragma unroll
    for (int tt = 0; tt < 4; ++tt) {
        int t = tg * 4 + tt;
        int key = t * 64 + c16 * 4;
        int4v   m  = *(const int4v*)(mrow + key);
        float4v bb = *(const float4v*)(brow + key);
        half4v o;
        o[0] = m[0] ? (_Float16)(bb[0] * LOG2E) : (_Float16)(-1500.0f);
        o[1] = m[1] ? (_Float16)(bb[1] * LOG2E) : (_Float16)(-1500.0f);
        o[2] = m[2] ? (_Float16)(bb[2] * LOG2E) : (_Float16)(-1500.0f);
        o[3] = m[3] ? (_Float16)(bb[3] * LOG2E) : (_Float16)(-1500.0f);
        *(half4v*)(obase + t * 1024) = o;
    }
}

// BODY: one loop1 iteration for tile T (T must be a LITERAL so puh[T] stays
// in registers).
#define BODY(T, MV)                                                           \
    {                                                                         \
        const _Float16* kb_ = kbw + ((T) & 1) * 1024;                         \
        const _Float16* vb_ = vbw + ((T) & 1) * 1024;                         \
        half8 bk0_ = *(const half8*)(kb_ + kro + ks0);                        \
        half8 bk1_ = *(const half8*)(kb_ + kro + ks1);                        \
        float4v acc_;                                                         \
        acc_[0] = (float)(MV)[0]; acc_[1] = (float)(MV)[1];                   \
        acc_[2] = (float)(MV)[2]; acc_[3] = (float)(MV)[3];                   \
        __builtin_amdgcn_s_setprio(1);                                        \
        acc_ = __builtin_amdgcn_mfma_f32_16x16x32_f16(bk0_, aq0, acc_, 0, 0, 0); \
        acc_ = __builtin_amdgcn_mfma_f32_16x16x32_f16(bk1_, aq1, acc_, 0, 0, 0); \
        __builtin_amdgcn_s_setprio(0);                                        \
        float e0_ = exp2f(acc_[0]), e1_ = exp2f(acc_[1]);                     \
        float e2_ = exp2f(acc_[2]), e3_ = exp2f(acc_[3]);                     \
        ls += (e0_ + e1_) + (e2_ + e3_);                                      \
        half4v ph_;                                                           \
        ph_[0] = (_Float16)(e0_ * 0.03125f); ph_[1] = (_Float16)(e1_ * 0.03125f); \
        ph_[2] = (_Float16)(e2_ * 0.03125f); ph_[3] = (_Float16)(e3_ * 0.03125f); \
        puh[(T)] = ph_;                                                       \
        half4v pv0_ = *(const half4v*)(vb_ + (cg +  0) * 16 + vro);           \
        half4v pv1_ = *(const half4v*)(vb_ + (cg + 16) * 16 + vro);           \
        half4v pv2_ = *(const half4v*)(vb_ + (cg + 32) * 16 + vro);           \
        half4v pv3_ = *(const half4v*)(vb_ + (cg + 48) * 16 + vro);           \
        __builtin_amdgcn_s_setprio(1);                                        \
        oa0 = __builtin_amdgcn_mfma_f32_16x16x16f16(ph_, pv0_, oa0, 0, 0, 0); \
        oa1 = __builtin_amdgcn_mfma_f32_16x16x16f16(ph_, pv1_, oa1, 0, 0, 0); \
        oa2 = __builtin_amdgcn_mfma_f32_16x16x16f16(ph_, pv2_, oa2, 0, 0, 0); \
        oa3 = __builtin_amdgcn_mfma_f32_16x16x16f16(ph_, pv3_, oa3, 0, 0, 0); \
        __builtin_amdgcn_s_setprio(0);                                        \
    }

// Phase A step (literal T): prefetch T+1, wait ledger (st(T)4 + m(T)1 drained,
// st(T+1)4 + m(T+1)1 in flight), compute T.
#define PA(T)                                                                 \
    if ((T) + 1 < NT) {                                                       \
        stage((T) + 1, ((T) & 1) ^ 1);                                        \
        mnxt = *(const half4v*)(mg0 + (size_t)((T) + 1) * 1024 + moff);       \
        WAITV(5);                                                             \
    } else { WAITV(0); }                                                      \
    BODY((T), mcur);                                                          \
    mcur = mnxt;

// Phase B: store group J (qt0 tiles 2J,2J+1) || loop1(qt1) iters 2J,2J+1.
// Ledger (incl. m-loads): before BODY(2J): Q=[st(2J)4,m(2J)1,NT2,st(2J+1)4,
// m(2J+1)1]=12, WAITV(7) drains st(2J)+m(2J). Before BODY(2J+1): WAITV(5)
// drains NT2+... leaving st(2J+2)4+m(2J+2)1.
#define PBST(J, TL)                                                           \
    {                                                                         \
        half4v p4_ = puh[2*(J)+(TL)];                                         \
        float4v pn_;                                                          \
        pn_[0] = (float)p4_[0] * rl0; pn_[1] = (float)p4_[1] * rl0;           \
        pn_[2] = (float)p4_[2] * rl0; pn_[3] = (float)p4_[3] * rl0;           \
        int g_ = (TL) * 16 + w * 4 + grp;                                     \
        *(float4v*)(t32B + cg * 128 + ((g_ ^ (cg & 7)) * 4)) = pn_;           \
    }
#define PBRD(J, K)                                                            \
    {                                                                         \
        int gr_ = ((K) * 16 + sjj) ^ (srow & 7);                              \
        float4v s_ = *(const float4v*)(t32B + srow * 128 + gr_ * 4);          \
        __builtin_nontemporal_store(s_,                                       \
            (float4v*)(arow0 + (size_t)srow * L + (J) * 128 + ((K) * 16 + sjj) * 4)); \
    }
#define PB(J)                                                                 \
    PBST(J, 0) PBST(J, 1)                                                     \
    WAITL(); BAR();                                                           \
    PBRD(J, 0) PBRD(J, 1)                                                     \
    BAR();                                                                    \
    if (2*(J) + 1 < NT) {                                                     \
        stage(2*(J) + 1, ((2*(J)) & 1) ^ 1);                                  \
        mnxt = *(const half4v*)(mg1 + (size_t)(2*(J) + 1) * 1024 + moff);     \
        WAITV(7);                                                             \
    } else { WAITV(0); }                                                      \
    BODY(2*(J), mcur);                                                        \
    mcur = mnxt;                                                              \
    if (2*(J) + 2 < NT) {                                                     \
        stage(2*(J) + 2, ((2*(J) + 1) & 1) ^ 1);                              \
        mnxt = *(const half4v*)(mg1 + (size_t)(2*(J) + 2) * 1024 + moff);     \
        WAITV(5);                                                             \
    } else { WAITV(0); }                                                      \
    BODY(2*(J) + 1, mcur);                                                    \
    mcur = mnxt;

// Phase C: R13 store loop, literal PH.
#define PCW(PH, I)                                                            \
    {                                                                         \
        half4v p4_ = puh[(PH)*4 + (I)];                                       \
        float4v pn_;                                                          \
        pn_[0] = (float)p4_[0] * rl1; pn_[1] = (float)p4_[1] * rl1;           \
        pn_[2] = (float)p4_[2] * rl1; pn_[3] = (float)p4_[3] * rl1;           \
        int g_ = ((I) * 16 + gbase) ^ (cg & 7);                               \
        *(float4v*)(tbC + cg * 256 + g_ * 4) = pn_;                           \
    }
#define PCR(PH, K)                                                            \
    {                                                                         \
        int g_ = (sjj + 16 * (K)) ^ (srow & 7);                               \
        float4v s_ = *(const float4v*)(tbC + srow * 256 + g_ * 4);            \
        __builtin_nontemporal_store(s_,                                       \
            (float4v*)(arow1 + (size_t)srow * L + (PH) * 256 + (sjj + 16 * (K)) * 4)); \
    }
#define PC(PH)                                                                \
    {                                                                         \
        float* tbC = t32C + ((PH) & 1) * 4096;                                \
        PCW(PH, 0) PCW(PH, 1) PCW(PH, 2) PCW(PH, 3)                           \
        WAITL(); BAR();                                                       \
        PCR(PH, 0) PCR(PH, 1) PCR(PH, 2) PCR(PH, 3)                           \
    }

// ---------------- fused attention: 2 q-tiles/block, phase-overlapped ----------------
// launch_bounds(256,3): 170-VGPR budget. R15-R17's spill was the 128-VGPR cap
// of (256,4) vs phase-B's ~150 live regs -- clang demoted puh[] (64 regs) to
// scratch wholesale. 3 blocks/CU (LDS would allow 4; VGPR binds).
__global__ __launch_bounds__(256, 3) void attn_fused(const _Float16* __restrict__ qh,
                                                     const _Float16* __restrict__ kh,
                                                     const _Float16* __restrict__ vt,
                                                     const _Float16* __restrict__ mbh,
                                                     float* __restrict__ out_ho,
                                                     float* __restrict__ out_attn) {
    __shared__ __align__(16) char arena[40960];

    int p  = blockIdx.x;                  // XCD x: 4 heads of one b
    int l  = (p & 7) * 256 + (p >> 3);
    int b  = l >> 10, h = (l >> 6) & 15, qp = l & 63;
    int bh = b * NH + h;
    int q0 = qp * 32;

    int tid = threadIdx.x, w = tid >> 6, lane = tid & 63;
    int cg = lane & 15, grp = lane >> 4;

    const _Float16* kg  = kh  + (size_t)bh * L * D;
    const _Float16* vg  = vt  + (size_t)bh * 131072;
    const _Float16* mg0 = mbh + (size_t)(b * 128 + qp * 2) * 32768;
    const _Float16* mg1 = mg0 + 32768;
    const _Float16* qg  = qh  + ((size_t)bh * L + q0) * D;

    _Float16* kbw   = (_Float16*)(arena)         + w * 2048;  // 2 bufs x 1024 halfs
    _Float16* vbw   = (_Float16*)(arena + 16384) + w * 2048;
    float*    t32B  = (float*)(arena + 32768);                // [16][128] (phase B)
    float*    lpart = (float*)(arena + 32768);                // alias, boundaries only
    float*    rls   = (float*)(arena + 33024);                // alias, boundaries only

    const int r8  = lane >> 3;
    const int kch = ((lane & 7) ^ r8) * 8;

    auto stage = [&](int t, int bs) {
        int kb = t * 4 + w;
        int k0 = kb * 16;
        _Float16* kd = kbw + bs * 1024;
        gload16(kg + (size_t)(k0 +     r8) * D + kch, kd);
        gload16(kg + (size_t)(k0 + 8 + r8) * D + kch, kd + 512);
        _Float16* vd = vbw + bs * 1024;
        const _Float16* vs = vg + (size_t)kb * 1024;
        gload16(vs + lane * 8, vd);
        gload16(vs + 512 + lane * 8, vd + 512);
    };

    const int kro  = cg * 64;
    const int ks0  = ((grp)     ^ (cg & 7)) * 8;
    const int ks1  = ((4 + grp) ^ (cg & 7)) * 8;
    const int vro  = grp * 4;
    const int moff = w * 256 + cg * 16 + grp * 4;
    const int srow = tid >> 4, sjj = tid & 15;

    half8 aq0 = *(const half8*)(qg + cg * D + grp * 8);
    half8 aq1 = *(const half8*)(qg + cg * D + 32 + grp * 8);

    half4v puh[NT];
    float ls = 0.f;
    float4v oa0 = {0,0,0,0}, oa1 = {0,0,0,0}, oa2 = {0,0,0,0}, oa3 = {0,0,0,0};

    auto ho_epilogue = [&](int row0, float* ored) {
        float* orw = ored + w * 1088;     // [4][16][68]
#pragma unroll
        for (int r = 0; r < 4; ++r) {
            orw[(grp * 4 + r) * 68 +  0 + cg] = oa0[r];
            orw[(grp * 4 + r) * 68 + 16 + cg] = oa1[r];
            orw[(grp * 4 + r) * 68 + 32 + cg] = oa2[r];
            orw[(grp * 4 + r) * 68 + 48 + cg] = oa3[r];
        }
        __syncthreads();
        int qr = tid >> 4, d4 = (tid & 15) * 4;
        float4v s0 = *(const float4v*)(ored + 0 * 1088 + qr * 68 + d4);
        float4v s1 = *(const float4v*)(ored + 1 * 1088 + qr * 68 + d4);
        float4v s2 = *(const float4v*)(ored + 2 * 1088 + qr * 68 + d4);
        float4v s3 = *(const float4v*)(ored + 3 * 1088 + qr * 68 + d4);
        float rlo = rls[qr];
        float4v oo;
        oo[0] = ((s0[0] + s1[0]) + (s2[0] + s3[0])) * rlo;
        oo[1] = ((s0[1] + s1[1]) + (s2[1] + s3[1])) * rlo;
        oo[2] = ((s0[2] + s1[2]) + (s2[2] + s3[2])) * rlo;
        oo[3] = ((s0[3] + s1[3]) + (s2[3] + s3[3])) * rlo;
        __builtin_nontemporal_store(oo, (float4v*)(out_ho + ((size_t)bh * L + row0 + qr) * D + d4));
    };

    // ================= phase A: loop1(qt0), barrier-free =================
    half4v mcur, mnxt;
    stage(0, 0);
    mcur = *(const half4v*)(mg0 + moff);
    PA(0)  PA(1)  PA(2)  PA(3)  PA(4)  PA(5)  PA(6)  PA(7)
    PA(8)  PA(9)  PA(10) PA(11) PA(12) PA(13) PA(14) PA(15)
    PA(16) PA(17) PA(18) PA(19) PA(20) PA(21) PA(22) PA(23)
    PA(24) PA(25) PA(26) PA(27) PA(28) PA(29) PA(30) PA(31)

    ls += __shfl_xor(ls, 16);
    ls += __shfl_xor(ls, 32);
    if (grp == 0) lpart[w * 16 + cg] = ls;
    __syncthreads();
    float rl0 = 32.0f / ((lpart[cg] + lpart[16 + cg]) + (lpart[32 + cg] + lpart[48 + cg]));
    if (w == 0 && grp == 0) rls[cg] = rl0;
    __syncthreads();
    ho_epilogue(q0, (float*)arena);       // ored aliases staging (dead)
    __syncthreads();                       // before qt1 staging overwrites

    // ================= phase B: stores(qt0) || loop1(qt1) =================
    aq0 = *(const half8*)(qg + (16 + cg) * D + grp * 8);
    aq1 = *(const half8*)(qg + (16 + cg) * D + 32 + grp * 8);
    oa0 = oa1 = oa2 = oa3 = float4v{0, 0, 0, 0};
    ls = 0.f;
    float* arow0 = out_attn + ((size_t)bh * L + q0) * L;

    stage(0, 0);
    mcur = *(const half4v*)(mg1 + moff);
    PB(0)  PB(1)  PB(2)  PB(3)  PB(4)  PB(5)  PB(6)  PB(7)
    PB(8)  PB(9)  PB(10) PB(11) PB(12) PB(13) PB(14) PB(15)

    ls += __shfl_xor(ls, 16);
    ls += __shfl_xor(ls, 32);
    if (grp == 0) lpart[w * 16 + cg] = ls;
    __syncthreads();
    float rl1 = 32.0f / ((lpart[cg] + lpart[16 + cg]) + (lpart[32 + cg] + lpart[48 + cg]));
    if (w == 0 && grp == 0) rls[cg] = rl1;
    __syncthreads();
    ho_epilogue(q0 + 16, (float*)arena);
    __syncthreads();                       // before t32C overwrites ored

    // ================= phase C: loop2(qt1), R13 store loop =================
    float* arow1 = out_attn + ((size_t)bh * L + q0 + 16) * L;
    float* t32C  = (float*)arena;          // dbuf [2][16][256]
    const int gbase = w * 4 + grp;
    PC(0) PC(1) PC(2) PC(3) PC(4) PC(5) PC(6) PC(7)
}

extern "C" void kernel_launch(void* const* d_in, const int* in_sizes, int n_in,
                              void* d_out, int out_size, void* d_ws, size_t ws_size,
                              hipStream_t stream) {
    const float* q    = (const float*)d_in[0];
    const float* k    = (const float*)d_in[1];
    const float* v    = (const float*)d_in[2];
    const int*   mask = (const int*)d_in[3];
    const float* bias = (const float*)d_in[4];

    float* ho   = (float*)d_out;
    float* attn = (float*)d_out + (size_t)NB * NH * L * D;

    char* ws = (char*)d_ws;
    _Float16* qh  = (_Float16*)(ws);                       //  8 MB
    _Float16* kh  = (_Float16*)(ws + ((size_t)8  << 20));  //  8 MB
    _Float16* vt  = (_Float16*)(ws + ((size_t)16 << 20));  //  8 MB (tiled)
    _Float16* mbh = (_Float16*)(ws + ((size_t)24 << 20));  // 16.8 MB (tiled)
    (void)in_sizes; (void)n_in; (void)out_size; (void)ws_size;

    prep_qk<<<2048, 256, 0, stream>>>(q, k, qh, kh);
    prep_vt<<<1024, 256, 0, stream>>>(v, vt);
    prep_mbh<<<2048, 256, 0, stream>>>(mask, bias, mbh);
    attn_fused<<<2048, 256, 0, stream>>>(qh, kh, vt, mbh, ho, attn);
}

// Round 19
// 191.953 us; speedup vs baseline: 2.9850x; 2.2473x over previous
//
#include <hip/hip_runtime.h>

#define L  2048
#define D  64
#define NH 16
#define NB 2
#define KT 64
#define NT 32
#define LOG2E 1.44269504088896f

using half8   = _Float16 __attribute__((ext_vector_type(8)));
using half4v  = _Float16 __attribute__((ext_vector_type(4)));
using float4v = float    __attribute__((ext_vector_type(4)));
using int4v   = int      __attribute__((ext_vector_type(4)));

#define BAR()    asm volatile("s_barrier" ::: "memory")
#define WAITV(n) asm volatile("s_waitcnt vmcnt(" #n ")" ::: "memory")
#define WAITL()  asm volatile("s_waitcnt lgkmcnt(0)" ::: "memory")

__device__ __forceinline__ void gload16(const void* g, void* l) {
    __builtin_amdgcn_global_load_lds((const __attribute__((address_space(1))) void*)g,
                                     (__attribute__((address_space(3))) void*)l, 16, 0, 0);
}
__device__ __forceinline__ void gload4(const void* g, void* l) {
    __builtin_amdgcn_global_load_lds((const __attribute__((address_space(1))) void*)g,
                                     (__attribute__((address_space(3))) void*)l, 4, 0, 0);
}

// ---------------- precompute: qh = fp16(q * log2e/8), kh = fp16(k) ----------------
__global__ __launch_bounds__(256) void prep_qk(const float* __restrict__ q,
                                               const float* __restrict__ k,
                                               _Float16* __restrict__ qh,
                                               _Float16* __restrict__ kh) {
    int i = (blockIdx.x * 256 + threadIdx.x) * 8;
    float4v a0 = *(const float4v*)(q + i);
    float4v a1 = *(const float4v*)(q + i + 4);
    float4v b0 = *(const float4v*)(k + i);
    float4v b1 = *(const float4v*)(k + i + 4);
    half8 qo, ko;
    const float s = 0.125f * LOG2E;
#pragma unroll
    for (int j = 0; j < 4; ++j) {
        qo[j]     = (_Float16)(a0[j] * s);
        qo[4 + j] = (_Float16)(a1[j] * s);
        ko[j]     = (_Float16)b0[j];
        ko[4 + j] = (_Float16)b1[j];
    }
    *(half8*)(qh + i) = qo;
    *(half8*)(kh + i) = ko;
}

// ------- precompute: vt2[bh][kb(128)][d(64)][kl(16)] = fp16(v[b,h,kb*16+kl,d]) -------
__global__ __launch_bounds__(256) void prep_vt(const float* __restrict__ v,
                                               _Float16* __restrict__ vt) {
    __shared__ float tile[64][65];
    int bh = blockIdx.x >> 5;
    int l0 = (blockIdx.x & 31) * 64;
    const float* vb = v + (size_t)bh * L * D + (size_t)l0 * D;
    int row = threadIdx.x >> 2, c0 = (threadIdx.x & 3) * 16;
#pragma unroll
    for (int j = 0; j < 16; j += 4) {
        float4v t4 = *(const float4v*)(vb + row * D + c0 + j);
        tile[row][c0 + j + 0] = t4[0];
        tile[row][c0 + j + 1] = t4[1];
        tile[row][c0 + j + 2] = t4[2];
        tile[row][c0 + j + 3] = t4[3];
    }
    __syncthreads();
    int d = threadIdx.x >> 2, kbl = threadIdx.x & 3;
    int lq = kbl * 16;
    _Float16* ob = vt + (((size_t)bh * 128 + (l0 >> 4) + kbl) * 64 + d) * 16;
    half8 o0, o1;
#pragma unroll
    for (int j = 0; j < 8; ++j) {
        o0[j] = (_Float16)tile[lq + j][d];
        o1[j] = (_Float16)tile[lq + 8 + j][d];
    }
    *(half8*)(ob)     = o0;
    *(half8*)(ob + 8) = o1;
}

// ------- precompute: mbh2[b][qt(128)][t(32)][w(4)][row(16)][kl(16)] -------
// 2048 blocks (bq x 8 t-groups): 8 blocks/CU parallelism.
__global__ __launch_bounds__(256) void prep_mbh(const int* __restrict__ mask,
                                                const float* __restrict__ bias,
                                                _Float16* __restrict__ mbh) {
    int blk = blockIdx.x;
    int bq = blk >> 3, tg = blk & 7;
    int b  = bq >> 7, qt = bq & 127;
    int row = threadIdx.x >> 4;             // 0..15
    int c16 = threadIdx.x & 15;             // 4-key chunk within 64-key tile
    const int*   mrow = mask + ((size_t)b * L + qt * 16 + row) * L;
    const float* brow = bias + ((size_t)b * L + qt * 16 + row) * L;
    _Float16* obase = mbh + (size_t)bq * 32768 + (c16 >> 2) * 256 + row * 16 + (c16 & 3) * 4;
#pragma unroll
    for (int tt = 0; tt < 4; ++tt) {
        int t = tg * 4 + tt;
        int key = t * 64 + c16 * 4;
        int4v   m  = *(const int4v*)(mrow + key);
        float4v bb = *(const float4v*)(brow + key);
        half4v o;
        o[0] = m[0] ? (_Float16)(bb[0] * LOG2E) : (_Float16)(-1500.0f);
        o[1] = m[1] ? (_Float16)(bb[1] * LOG2E) : (_Float16)(-1500.0f);
        o[2] = m[2] ? (_Float16)(bb[2] * LOG2E) : (_Float16)(-1500.0f);
        o[3] = m[3] ? (_Float16)(bb[3] * LOG2E) : (_Float16)(-1500.0f);
        *(half4v*)(obase + t * 1024) = o;
    }
}

// ---------------- fused attention (R13: best verified, 192.2 us) ----------------
// block = 16 q-rows, 4 waves; wave w owns key-block kb = t*4+w of every
// 64-key tile; wave-private dbuf staging, barrier-free loop 1.
// Loop 1: stage K(2x1KB contig)+V(2x1KB contig)+M(2x256B contig) -> QK ->
//   e=exp2 -> puh[t] fp16 regs -> PV accumulate (unnormalized).
// Loop 2: attn stores only: puh*rl -> t32 LDS dbuf (4 tiles/phase) ->
//   256B-contiguous NT stores.
__global__ __launch_bounds__(256, 4) void attn_fused(const _Float16* __restrict__ qh,
                                                     const _Float16* __restrict__ kh,
                                                     const _Float16* __restrict__ vt,
                                                     const _Float16* __restrict__ mbh,
                                                     float* __restrict__ out_ho,
                                                     float* __restrict__ out_attn) {
    __shared__ __align__(16) char arena[36864];
    __shared__ float lpart[4][16];
    __shared__ float rls[16];

    int p  = blockIdx.x;                  // XCD x: 4 heads of one b, all q-tiles
    int l  = (p & 7) * 512 + (p >> 3);
    int b  = l >> 11, h = (l >> 7) & 15, qt = l & 127;
    int bh = b * NH + h;
    int q0 = qt * 16;

    int tid = threadIdx.x, w = tid >> 6, lane = tid & 63;
    int cg = lane & 15, grp = lane >> 4;

    const _Float16* kg = kh  + (size_t)bh * L * D;             // [l][d]
    const _Float16* vg = vt  + (size_t)bh * 131072;            // [kb][d][kl]
    const _Float16* mg = mbh + (size_t)(b * 128 + qt) * 32768; // [t][w][row][kl]
    const _Float16* qg = qh  + ((size_t)bh * L + q0) * D;

    half8 aq0 = *(const half8*)(qg + cg * D + grp * 8);
    half8 aq1 = *(const half8*)(qg + cg * D + 32 + grp * 8);

    _Float16* kbw = (_Float16*)(arena)         + w * 2048;
    _Float16* vbw = (_Float16*)(arena + 16384) + w * 2048;
    _Float16* mbw = (_Float16*)(arena + 32768) + w * 512;

    const int r8  = lane >> 3;
    const int kch = ((lane & 7) ^ r8) * 8;        // K src d-chunk, XOR-preswizzled

    auto stage = [&](int t, int bs) {
        int kb = t * 4 + w;
        int k0 = kb * 16;
        _Float16* kd = kbw + bs * 1024;
        gload16(kg + (size_t)(k0 +     r8) * D + kch, kd);
        gload16(kg + (size_t)(k0 + 8 + r8) * D + kch, kd + 512);
        _Float16* vd = vbw + bs * 1024;
        const _Float16* vs = vg + (size_t)kb * 1024;
        gload16(vs + lane * 8, vd);
        gload16(vs + 512 + lane * 8, vd + 512);
        _Float16* md = mbw + bs * 256;
        const _Float16* ms = mg + (size_t)t * 1024 + w * 256;
        gload4(ms + lane * 2, md);
        gload4(ms + 128 + lane * 2, md + 128);
    };

    const int kro = cg * 64;
    const int ks0 = ((grp)     ^ (cg & 7)) * 8;
    const int ks1 = ((4 + grp) ^ (cg & 7)) * 8;
    const int mro = cg * 16 + grp * 4;
    const int vro = grp * 4;

    half4v puh[NT];                               // unnormalized e * 2^-5
    float ls = 0.f;
    float4v oa0 = {0.f,0.f,0.f,0.f}, oa1 = {0.f,0.f,0.f,0.f};
    float4v oa2 = {0.f,0.f,0.f,0.f}, oa3 = {0.f,0.f,0.f,0.f};

    // ---------------- loop 1: barrier-free QK + PV ----------------
    stage(0, 0);
#pragma unroll
    for (int t = 0; t < NT; ++t) {
        const int bs = t & 1;
        if (t + 1 < NT) { stage(t + 1, bs ^ 1); WAITV(6); }
        else            { WAITV(0); }
        const _Float16* kb = kbw + bs * 1024;
        const _Float16* mb = mbw + bs * 256;
        const _Float16* vb = vbw + bs * 1024;
        half8  bk0 = *(const half8*)(kb + kro + ks0);
        half8  bk1 = *(const half8*)(kb + kro + ks1);
        half4v m4  = *(const half4v*)(mb + mro);
        float4v acc;
        acc[0] = (float)m4[0]; acc[1] = (float)m4[1];
        acc[2] = (float)m4[2]; acc[3] = (float)m4[3];
        __builtin_amdgcn_s_setprio(1);
        acc = __builtin_amdgcn_mfma_f32_16x16x32_f16(bk0, aq0, acc, 0, 0, 0);
        acc = __builtin_amdgcn_mfma_f32_16x16x32_f16(bk1, aq1, acc, 0, 0, 0);
        __builtin_amdgcn_s_setprio(0);
        float e0 = exp2f(acc[0]), e1 = exp2f(acc[1]);
        float e2 = exp2f(acc[2]), e3 = exp2f(acc[3]);
        ls += (e0 + e1) + (e2 + e3);
        half4v ph;
        ph[0] = (_Float16)(e0 * 0.03125f); ph[1] = (_Float16)(e1 * 0.03125f);
        ph[2] = (_Float16)(e2 * 0.03125f); ph[3] = (_Float16)(e3 * 0.03125f);
        puh[t] = ph;
        half4v pv0 = *(const half4v*)(vb + (cg +  0) * 16 + vro);
        half4v pv1 = *(const half4v*)(vb + (cg + 16) * 16 + vro);
        half4v pv2 = *(const half4v*)(vb + (cg + 32) * 16 + vro);
        half4v pv3 = *(const half4v*)(vb + (cg + 48) * 16 + vro);
        __builtin_amdgcn_s_setprio(1);
        oa0 = __builtin_amdgcn_mfma_f32_16x16x16f16(ph, pv0, oa0, 0, 0, 0);
        oa1 = __builtin_amdgcn_mfma_f32_16x16x16f16(ph, pv1, oa1, 0, 0, 0);
        oa2 = __builtin_amdgcn_mfma_f32_16x16x16f16(ph, pv2, oa2, 0, 0, 0);
        oa3 = __builtin_amdgcn_mfma_f32_16x16x16f16(ph, pv3, oa3, 0, 0, 0);
        __builtin_amdgcn_s_setprio(0);
    }

    // ---------------- l reduce ----------------
    ls += __shfl_xor(ls, 16);
    ls += __shfl_xor(ls, 32);
    if (grp == 0) lpart[w][cg] = ls;
    __syncthreads();
    float lt = (lpart[0][cg] + lpart[1][cg]) + (lpart[2][cg] + lpart[3][cg]);
    float rl = 32.0f / lt;
    if (w == 0 && grp == 0) rls[cg] = rl;

    // ---------------- O reduce across waves + ho store ----------------
    float* ored = (float*)(arena + 8192);
    float* orw  = ored + w * (16 * 68);
#pragma unroll
    for (int r = 0; r < 4; ++r) {
        orw[(grp * 4 + r) * 68 +  0 + cg] = oa0[r];
        orw[(grp * 4 + r) * 68 + 16 + cg] = oa1[r];
        orw[(grp * 4 + r) * 68 + 32 + cg] = oa2[r];
        orw[(grp * 4 + r) * 68 + 48 + cg] = oa3[r];
    }
    __syncthreads();
    {
        int qr = tid >> 4, d4 = (tid & 15) * 4;
        float4v s0 = *(const float4v*)(ored + 0 * 1088 + qr * 68 + d4);
        float4v s1 = *(const float4v*)(ored + 1 * 1088 + qr * 68 + d4);
        float4v s2 = *(const float4v*)(ored + 2 * 1088 + qr * 68 + d4);
        float4v s3 = *(const float4v*)(ored + 3 * 1088 + qr * 68 + d4);
        float rlo = rls[qr];
        float4v oo;
        oo[0] = ((s0[0] + s1[0]) + (s2[0] + s3[0])) * rlo;
        oo[1] = ((s0[1] + s1[1]) + (s2[1] + s3[1])) * rlo;
        oo[2] = ((s0[2] + s1[2]) + (s2[2] + s3[2])) * rlo;
        oo[3] = ((s0[3] + s1[3]) + (s2[3] + s3[3])) * rlo;
        __builtin_nontemporal_store(oo, (float4v*)(out_ho + ((size_t)bh * L + q0 + qr) * D + d4));
    }
    __syncthreads();                       // ored readers done before t32 overwrites

    // ---------------- loop 2: attn stores, 4 tiles (256 keys) per phase ----------------
    float* arow = out_attn + ((size_t)bh * L + q0) * L;
    float* t32f = (float*)arena;                       // dbuf [2][16][256] f32
    const int gbase = w * 4 + grp;
    const int swrow = tid >> 4, jj = tid & 15;

#pragma unroll
    for (int ph = 0; ph < 8; ++ph) {
        float* tb = t32f + (ph & 1) * 4096;
#pragma unroll
        for (int i = 0; i < 4; ++i) {
            const int tt = ph * 4 + i;
            float4v pn;
            pn[0] = (float)puh[tt][0] * rl; pn[1] = (float)puh[tt][1] * rl;
            pn[2] = (float)puh[tt][2] * rl; pn[3] = (float)puh[tt][3] * rl;
            int g = (i * 16 + gbase) ^ (cg & 7);
            *(float4v*)(tb + cg * 256 + g * 4) = pn;
        }
        WAITL();
        BAR();
#pragma unroll
        for (int k = 0; k < 4; ++k) {
            int g = (jj + 16 * k) ^ (swrow & 7);
            float4v s = *(const float4v*)(tb + swrow * 256 + g * 4);
            __builtin_nontemporal_store(s,
                (float4v*)(arow + (size_t)swrow * L + ph * 256 + (jj + 16 * k) * 4));
        }
    }
}

extern "C" void kernel_launch(void* const* d_in, const int* in_sizes, int n_in,
                              void* d_out, int out_size, void* d_ws, size_t ws_size,
                              hipStream_t stream) {
    const float* q    = (const float*)d_in[0];
    const float* k    = (const float*)d_in[1];
    const float* v    = (const float*)d_in[2];
    const int*   mask = (const int*)d_in[3];
    const float* bias = (const float*)d_in[4];

    float* ho   = (float*)d_out;
    float* attn = (float*)d_out + (size_t)NB * NH * L * D;

    char* ws = (char*)d_ws;
    _Float16* qh  = (_Float16*)(ws);                       //  8 MB
    _Float16* kh  = (_Float16*)(ws + ((size_t)8  << 20));  //  8 MB
    _Float16* vt  = (_Float16*)(ws + ((size_t)16 << 20));  //  8 MB (tiled)
    _Float16* mbh = (_Float16*)(ws + ((size_t)24 << 20));  // 16.8 MB (tiled)
    (void)in_sizes; (void)n_in; (void)out_size; (void)ws_size;

    prep_qk<<<2048, 256, 0, stream>>>(q, k, qh, kh);
    prep_vt<<<1024, 256, 0, stream>>>(v, vt);
    prep_mbh<<<2048, 256, 0, stream>>>(mask, bias, mbh);
    attn_fused<<<4096, 256, 0, stream>>>(qh, kh, vt, mbh, ho, attn);
}